// Round 3
// baseline (4729.000 us; speedup 1.0000x reference)
//
#include <hip/hip_runtime.h>

// VanillaRNN B=256 S=1024 H=512 C=10, fp32 in/out.
// Arch R3 (bisection build): 16 persistent workgroups (16 batch rows), 16
// waves. MFMA core only; all scaffolding simplified to the dumbest correct
// form: tanhf(), no pred fold/lag/epilogue, plain x loads, 3 barriers/step.
// w_hh resident: per wave 2 N-tiles, K-blocks 0..11 in VGPRs, 12..15 in LDS.

typedef _Float16 half8 __attribute__((ext_vector_type(8)));
typedef float   float4v __attribute__((ext_vector_type(4)));

#define NTHREADS 1024         // 16 waves
#define NW 16
#define BT 16                 // batch rows per workgroup
#define HH 512
#define SS 1024
#define CC 10
#define KB_TOT 16             // 512 / 32
#define KB_REG 12             // K-blocks in registers (96 VGPRs)
#define KB_LDS 4              // K-blocks in LDS

#define HSTRIDE 520           // fp16 elems per h row (pad: bank spread)
#define W_OFF 0
#define W_BYTES (32 * KB_LDS * 1024)     // 131072
#define H_OFF  W_BYTES
#define H_BYTES (BT * HSTRIDE * 2)       // 16640
#define P_OFF  (H_OFF + H_BYTES)         // 147712
#define PBS    192                       // floats per wave slot
#define P_BYTES (NW * PBS * 4)           // 12288
#define SMEM_BYTES (P_OFF + P_BYTES)     // 160000 <= 163840

__global__ __launch_bounds__(NTHREADS, 4)
void rnn_persist(const float* __restrict__ x,
                 const float* __restrict__ w_hx,
                 const float* __restrict__ w_hh,
                 const float* __restrict__ w_ph,
                 const float* __restrict__ b_h,
                 const float* __restrict__ b_p,
                 float* __restrict__ out)
{
    extern __shared__ char smem[];
    _Float16* hl = (_Float16*)(smem + H_OFF);
    float*    pb = (float*)(smem + P_OFF);

    const int tid  = threadIdx.x;
    const int lane = tid & 63;
    const int wv   = tid >> 6;        // wave id 0..15
    const int n    = lane & 15;       // A-row m / B-col n / D-col n
    const int quad = lane >> 4;       // k-quadrant; D-rows quad*4+r
    const int rowbase = blockIdx.x * BT;

    // ---------------- one-time: resident weights ----------------
    // B-frag: lane(n,quad) holds w_hh[ntile*16+n][kb*32 + quad*8 + e]
    half8 wr[2][KB_REG];              // 96 VGPRs
    #pragma unroll
    for (int j = 0; j < 2; ++j) {
        const float* wrow = w_hh + ((wv * 2 + j) * 16 + n) * HH;
        #pragma unroll
        for (int kb = 0; kb < KB_REG; ++kb) {
            const float* p = wrow + kb * 32 + quad * 8;
            half8 hv;
            #pragma unroll
            for (int e = 0; e < 8; ++e) hv[e] = (_Float16)p[e];
            wr[j][kb] = hv;
        }
    }
    #pragma unroll
    for (int j = 0; j < 2; ++j) {     // K-blocks 12..15 -> LDS cells (1 KB)
        const float* wrow = w_hh + ((wv * 2 + j) * 16 + n) * HH;
        #pragma unroll
        for (int kbs = 0; kbs < KB_LDS; ++kbs) {
            const float* p = wrow + (KB_REG + kbs) * 32 + quad * 8;
            half8 hv;
            #pragma unroll
            for (int e = 0; e < 8; ++e) hv[e] = (_Float16)p[e];
            *(half8*)(smem + W_OFF + ((wv * 2 + j) * KB_LDS + kbs) * 1024
                      + n * 64 + quad * 16) = hv;
        }
    }
    float wx2[2], bh2[2];
    #pragma unroll
    for (int j = 0; j < 2; ++j) {
        int ng = (wv * 2 + j) * 16 + n;
        wx2[j] = w_hx[ng];
        bh2[j] = b_h[ng];
    }
    // pred B-frag: wave wv owns pred K-block wv; cols c<10 valid, rest zero
    half8 wp;
    {
        half8 hv;
        #pragma unroll
        for (int e = 0; e < 8; ++e) hv[e] = (_Float16)0.f;
        if (n < CC) {
            const float* p = w_ph + n * HH + wv * 32 + quad * 8;
            #pragma unroll
            for (int e = 0; e < 8; ++e) hv[e] = (_Float16)p[e];
        }
        wp = hv;
    }

    // zero h_0
    for (int i = tid; i < BT * HSTRIDE; i += NTHREADS) hl[i] = (_Float16)0.f;
    __syncthreads();

    const int aoff = n * (HSTRIDE * 2) + quad * 16;   // A-frag byte base
    const int woff = (wv * 2) * (KB_LDS * 1024) + n * 64 + quad * 16;

    #pragma unroll 1
    for (int t = 0; t < SS; ++t) {
        // x for this step, rows quad*4+r (plain loads — diagnostic build)
        float xr[4];
        #pragma unroll
        for (int r = 0; r < 4; ++r)
            xr[r] = x[(rowbase + quad * 4 + r) * SS + t];

        // acc init: z = x_t * wx + b_h   (D rows quad*4+r, col ntile*16+n)
        float4v acc[2];
        #pragma unroll
        for (int j = 0; j < 2; ++j)
            #pragma unroll
            for (int r = 0; r < 4; ++r) acc[j][r] = xr[r] * wx2[j] + bh2[j];

        // K loop: z += h_prev @ w_hh^T
        #pragma unroll
        for (int kb = 0; kb < KB_TOT; ++kb) {
            half8 a = *(const half8*)(smem + H_OFF + aoff + kb * 64);
            if (kb < KB_REG) {
                #pragma unroll
                for (int j = 0; j < 2; ++j)
                    acc[j] = __builtin_amdgcn_mfma_f32_16x16x32_f16(a, wr[j][kb], acc[j], 0, 0, 0);
            } else {
                #pragma unroll
                for (int j = 0; j < 2; ++j) {
                    half8 b = *(const half8*)(smem + W_OFF + woff
                                              + (j * KB_LDS + (kb - KB_REG)) * 1024);
                    acc[j] = __builtin_amdgcn_mfma_f32_16x16x32_f16(a, b, acc[j], 0, 0, 0);
                }
            }
        }

        __syncthreads();              // B1: all A-reads of h_prev done

        // h_new = tanh(z) -> fp16 -> LDS (C/D layout: row=quad*4+r, col=n)
        #pragma unroll
        for (int j = 0; j < 2; ++j) {
            int col = (wv * 2 + j) * 16 + n;
            #pragma unroll
            for (int r = 0; r < 4; ++r)
                hl[(quad * 4 + r) * HSTRIDE + col] = (_Float16)tanhf(acc[j][r]);
        }

        __syncthreads();              // B2: h_t visible to all waves

        // pred_t = h_t @ w_ph^T (unlagged): wave wv does K-block wv
        {
            half8 a2 = *(const half8*)(smem + H_OFF + aoff + wv * 64);
            float4v pa;
            #pragma unroll
            for (int r = 0; r < 4; ++r) pa[r] = 0.f;
            pa = __builtin_amdgcn_mfma_f32_16x16x32_f16(a2, wp, pa, 0, 0, 0);
            if (n < CC) {
                #pragma unroll
                for (int r = 0; r < 4; ++r)
                    pb[wv * PBS + (quad * 4 + r) * 12 + n] = pa[r];
            }
        }

        __syncthreads();              // B3: pred partials visible

        if (tid < BT * CC) {          // reduce 16 partials, store pred_t
            int m = tid / CC, c = tid - m * CC;
            float s = b_p[c];
            #pragma unroll
            for (int w = 0; w < NW; ++w) s += pb[w * PBS + m * 12 + c];
            out[((rowbase + m) * SS + t) * CC + c] = s;
        }
    }
}

extern "C" void kernel_launch(void* const* d_in, const int* in_sizes, int n_in,
                              void* d_out, int out_size, void* d_ws, size_t ws_size,
                              hipStream_t stream)
{
    (void)in_sizes; (void)n_in; (void)d_ws; (void)ws_size; (void)out_size;
    const float* x    = (const float*)d_in[0];
    const float* w_hx = (const float*)d_in[1];
    const float* w_hh = (const float*)d_in[2];
    const float* w_ph = (const float*)d_in[3];
    const float* b_h  = (const float*)d_in[4];
    const float* b_p  = (const float*)d_in[5];
    float* out = (float*)d_out;

    (void)hipFuncSetAttribute((const void*)rnn_persist,
                              hipFuncAttributeMaxDynamicSharedMemorySize,
                              SMEM_BYTES);
    rnn_persist<<<dim3(256 / BT), dim3(NTHREADS), SMEM_BYTES, stream>>>(
        x, w_hx, w_hh, w_ph, b_h, b_p, out);
}

// Round 4
// 3473.779 us; speedup vs baseline: 1.3613x; 1.3613x over previous
//
#include <hip/hip_runtime.h>

// VanillaRNN B=256 S=1024 H=512 C=10, fp32 in/out.
// Arch R4: 16 persistent workgroups (16 batch rows), 8 waves x 4 N-tiles.
// Fixes R3's register-spill cliff: 16 waves gave 128-reg/wave unified budget
// vs ~160 demand -> wr spilled to scratch (VGPR_Count=64, L2 refills ~2-3
// us/step). 8 waves @ __launch_bounds__(512,2) -> 256-reg budget, wr[4][12]
// = 192 regs fits. Scaffolding unchanged from the PASSING R3: tanhf, unlagged
// pred, 3 unconditional barriers. x*wx folded in AFTER the K-loop so the
// global x load latency hides under the MFMAs.

typedef _Float16 half8 __attribute__((ext_vector_type(8)));
typedef float   float4v __attribute__((ext_vector_type(4)));

#define NTHREADS 512          // 8 waves
#define NW 8
#define BT 16                 // batch rows per workgroup
#define HH 512
#define SS 1024
#define CC 10
#define KB_TOT 16             // 512 / 32
#define KB_REG 12             // K-blocks in registers (4 N-tiles * 12 = 192)
#define KB_LDS 4              // K-blocks in LDS

#define HSTRIDE 520           // fp16 elems per h row (pad: bank spread)
#define W_OFF 0
#define W_BYTES (32 * KB_LDS * 1024)     // 131072
#define H_OFF  W_BYTES
#define H_BYTES (BT * HSTRIDE * 2)       // 16640
#define P_OFF  (H_OFF + H_BYTES)         // 147712
#define PBS    192                       // floats per wave slot (16 rows * 12)
#define P_BYTES (NW * PBS * 4)           // 6144
#define SMEM_BYTES (P_OFF + P_BYTES)     // 153856 <= 163840

__global__ __launch_bounds__(NTHREADS, 2)
void rnn_persist(const float* __restrict__ x,
                 const float* __restrict__ w_hx,
                 const float* __restrict__ w_hh,
                 const float* __restrict__ w_ph,
                 const float* __restrict__ b_h,
                 const float* __restrict__ b_p,
                 float* __restrict__ out)
{
    extern __shared__ char smem[];
    _Float16* hl = (_Float16*)(smem + H_OFF);
    float*    pb = (float*)(smem + P_OFF);

    const int tid  = threadIdx.x;
    const int lane = tid & 63;
    const int wv   = tid >> 6;        // wave id 0..7
    const int n    = lane & 15;       // A-row m / B-col n / D-col n
    const int quad = lane >> 4;       // k-quadrant; D-rows quad*4+r
    const int rowbase = blockIdx.x * BT;

    // ---------------- one-time: resident weights ----------------
    // B-frag: lane(n,quad) holds w_hh[ntile*16+n][kb*32 + quad*8 + e]
    half8 wr[4][KB_REG];              // 192 regs: this wave's 4 N-tiles
    #pragma unroll
    for (int j = 0; j < 4; ++j) {
        const float* wrow = w_hh + ((wv * 4 + j) * 16 + n) * HH;
        #pragma unroll
        for (int kb = 0; kb < KB_REG; ++kb) {
            const float* p = wrow + kb * 32 + quad * 8;
            half8 hv;
            #pragma unroll
            for (int e = 0; e < 8; ++e) hv[e] = (_Float16)p[e];
            wr[j][kb] = hv;
        }
    }
    #pragma unroll
    for (int j = 0; j < 4; ++j) {     // K-blocks 12..15 -> LDS cells (1 KB)
        const float* wrow = w_hh + ((wv * 4 + j) * 16 + n) * HH;
        #pragma unroll
        for (int kbs = 0; kbs < KB_LDS; ++kbs) {
            const float* p = wrow + (KB_REG + kbs) * 32 + quad * 8;
            half8 hv;
            #pragma unroll
            for (int e = 0; e < 8; ++e) hv[e] = (_Float16)p[e];
            *(half8*)(smem + W_OFF + ((wv * 4 + j) * KB_LDS + kbs) * 1024
                      + n * 64 + quad * 16) = hv;
        }
    }
    float wx4[4], bh4[4];
    #pragma unroll
    for (int j = 0; j < 4; ++j) {
        int ng = (wv * 4 + j) * 16 + n;
        wx4[j] = w_hx[ng];
        bh4[j] = b_h[ng];
    }
    // pred B-frags: wave wv owns pred K-blocks 2wv, 2wv+1; cols c<10 valid
    half8 wp[2];
    #pragma unroll
    for (int i = 0; i < 2; ++i) {
        half8 hv;
        #pragma unroll
        for (int e = 0; e < 8; ++e) hv[e] = (_Float16)0.f;
        if (n < CC) {
            const float* p = w_ph + n * HH + (wv * 2 + i) * 32 + quad * 8;
            #pragma unroll
            for (int e = 0; e < 8; ++e) hv[e] = (_Float16)p[e];
        }
        wp[i] = hv;
    }

    // zero h_0
    for (int i = tid; i < BT * HSTRIDE; i += NTHREADS) hl[i] = (_Float16)0.f;
    __syncthreads();

    const int aoff = n * (HSTRIDE * 2) + quad * 16;   // A-frag byte base
    const int woff = (wv * 4) * (KB_LDS * 1024) + n * 64 + quad * 16;

    #pragma unroll 1
    for (int t = 0; t < SS; ++t) {
        // x for this step (rows quad*4+r) — issued early, consumed after the
        // K-loop so L2 latency hides under the MFMAs
        float xr[4];
        #pragma unroll
        for (int r = 0; r < 4; ++r)
            xr[r] = x[(rowbase + quad * 4 + r) * SS + t];

        // acc init: bias only (no load dependency)
        float4v acc[4];
        #pragma unroll
        for (int j = 0; j < 4; ++j)
            #pragma unroll
            for (int r = 0; r < 4; ++r) acc[j][r] = bh4[j];

        // K loop: z += h_prev @ w_hh^T
        #pragma unroll
        for (int kb = 0; kb < KB_TOT; ++kb) {
            half8 a = *(const half8*)(smem + H_OFF + aoff + kb * 64);
            if (kb < KB_REG) {
                #pragma unroll
                for (int j = 0; j < 4; ++j)
                    acc[j] = __builtin_amdgcn_mfma_f32_16x16x32_f16(a, wr[j][kb], acc[j], 0, 0, 0);
            } else {
                #pragma unroll
                for (int j = 0; j < 4; ++j) {
                    half8 b = *(const half8*)(smem + W_OFF + woff
                                              + (j * KB_LDS + (kb - KB_REG)) * 1024);
                    acc[j] = __builtin_amdgcn_mfma_f32_16x16x32_f16(a, b, acc[j], 0, 0, 0);
                }
            }
        }

        __syncthreads();              // B1: all A-reads of h_prev done

        // z += x_t * wx ; h_new = tanh(z) -> fp16 -> LDS
        #pragma unroll
        for (int j = 0; j < 4; ++j) {
            int col = (wv * 4 + j) * 16 + n;
            #pragma unroll
            for (int r = 0; r < 4; ++r) {
                float z = acc[j][r] + xr[r] * wx4[j];
                hl[(quad * 4 + r) * HSTRIDE + col] = (_Float16)tanhf(z);
            }
        }

        __syncthreads();              // B2: h_t visible to all waves

        // pred_t = h_t @ w_ph^T (unlagged): wave wv does K-blocks 2wv,2wv+1
        {
            float4v pa;
            #pragma unroll
            for (int r = 0; r < 4; ++r) pa[r] = 0.f;
            #pragma unroll
            for (int i = 0; i < 2; ++i) {
                half8 a2 = *(const half8*)(smem + H_OFF + aoff + (wv * 2 + i) * 64);
                pa = __builtin_amdgcn_mfma_f32_16x16x32_f16(a2, wp[i], pa, 0, 0, 0);
            }
            if (n < CC) {
                #pragma unroll
                for (int r = 0; r < 4; ++r)
                    pb[wv * PBS + (quad * 4 + r) * 12 + n] = pa[r];
            }
        }

        __syncthreads();              // B3: pred partials visible

        if (tid < BT * CC) {          // reduce 8 partials, store pred_t
            int m = tid / CC, c = tid - m * CC;
            float s = b_p[c];
            #pragma unroll
            for (int w = 0; w < NW; ++w) s += pb[w * PBS + m * 12 + c];
            out[((rowbase + m) * SS + t) * CC + c] = s;
        }
    }
}

extern "C" void kernel_launch(void* const* d_in, const int* in_sizes, int n_in,
                              void* d_out, int out_size, void* d_ws, size_t ws_size,
                              hipStream_t stream)
{
    (void)in_sizes; (void)n_in; (void)d_ws; (void)ws_size; (void)out_size;
    const float* x    = (const float*)d_in[0];
    const float* w_hx = (const float*)d_in[1];
    const float* w_hh = (const float*)d_in[2];
    const float* w_ph = (const float*)d_in[3];
    const float* b_h  = (const float*)d_in[4];
    const float* b_p  = (const float*)d_in[5];
    float* out = (float*)d_out;

    (void)hipFuncSetAttribute((const void*)rnn_persist,
                              hipFuncAttributeMaxDynamicSharedMemorySize,
                              SMEM_BYTES);
    rnn_persist<<<dim3(256 / BT), dim3(NTHREADS), SMEM_BYTES, stream>>>(
        x, w_hx, w_hh, w_ph, b_h, b_p, out);
}

// Round 5
// 2608.678 us; speedup vs baseline: 1.8128x; 1.3316x over previous
//
#include <hip/hip_runtime.h>

// VanillaRNN B=256 S=1024 H=512 C=10, fp32 in/out.
// Arch R5: identical to the PASSING R4 (16 WGs x 8 waves x 4 N-tiles,
// wr[4][12] in unified VGPR/AGPR, 3 barriers, unlagged pred) with ONE change:
// ocml tanhf -> exp2-based fast tanh (1 - 2/(e^{2z}+1), ~6 VALU inst vs ~35).
// R4 counters: active-CU VALUBusy ~33% dominated by tanhf; MFMA only ~26%.

typedef _Float16 half8 __attribute__((ext_vector_type(8)));
typedef float   float4v __attribute__((ext_vector_type(4)));

#define NTHREADS 512          // 8 waves
#define NW 8
#define BT 16                 // batch rows per workgroup
#define HH 512
#define SS 1024
#define CC 10
#define KB_TOT 16             // 512 / 32
#define KB_REG 12             // K-blocks in registers (4 N-tiles * 12 = 192)
#define KB_LDS 4              // K-blocks in LDS

#define HSTRIDE 520           // fp16 elems per h row (pad: bank spread)
#define W_OFF 0
#define W_BYTES (32 * KB_LDS * 1024)     // 131072
#define H_OFF  W_BYTES
#define H_BYTES (BT * HSTRIDE * 2)       // 16640
#define P_OFF  (H_OFF + H_BYTES)         // 147712
#define PBS    192                       // floats per wave slot (16 rows * 12)
#define P_BYTES (NW * PBS * 4)           // 6144
#define SMEM_BYTES (P_OFF + P_BYTES)     // 153856 <= 163840

// tanh(z) = 1 - 2/(e^{2z}+1); e^{2z} = exp2(z * 2/ln2). Exact at 0/+-inf,
// ~2e-7 rel error -- 2500x below the fp16 storage quantum (5e-4).
__device__ __forceinline__ float fast_tanh(float z) {
    float ez = __builtin_amdgcn_exp2f(z * 2.8853900817779268f);
    return 1.0f - 2.0f * __builtin_amdgcn_rcpf(ez + 1.0f);
}

__global__ __launch_bounds__(NTHREADS, 2)
void rnn_persist(const float* __restrict__ x,
                 const float* __restrict__ w_hx,
                 const float* __restrict__ w_hh,
                 const float* __restrict__ w_ph,
                 const float* __restrict__ b_h,
                 const float* __restrict__ b_p,
                 float* __restrict__ out)
{
    extern __shared__ char smem[];
    _Float16* hl = (_Float16*)(smem + H_OFF);
    float*    pb = (float*)(smem + P_OFF);

    const int tid  = threadIdx.x;
    const int lane = tid & 63;
    const int wv   = tid >> 6;        // wave id 0..7
    const int n    = lane & 15;       // A-row m / B-col n / D-col n
    const int quad = lane >> 4;       // k-quadrant; D-rows quad*4+r
    const int rowbase = blockIdx.x * BT;

    // ---------------- one-time: resident weights ----------------
    // B-frag: lane(n,quad) holds w_hh[ntile*16+n][kb*32 + quad*8 + e]
    half8 wr[4][KB_REG];              // 192 regs: this wave's 4 N-tiles
    #pragma unroll
    for (int j = 0; j < 4; ++j) {
        const float* wrow = w_hh + ((wv * 4 + j) * 16 + n) * HH;
        #pragma unroll
        for (int kb = 0; kb < KB_REG; ++kb) {
            const float* p = wrow + kb * 32 + quad * 8;
            half8 hv;
            #pragma unroll
            for (int e = 0; e < 8; ++e) hv[e] = (_Float16)p[e];
            wr[j][kb] = hv;
        }
    }
    #pragma unroll
    for (int j = 0; j < 4; ++j) {     // K-blocks 12..15 -> LDS cells (1 KB)
        const float* wrow = w_hh + ((wv * 4 + j) * 16 + n) * HH;
        #pragma unroll
        for (int kbs = 0; kbs < KB_LDS; ++kbs) {
            const float* p = wrow + (KB_REG + kbs) * 32 + quad * 8;
            half8 hv;
            #pragma unroll
            for (int e = 0; e < 8; ++e) hv[e] = (_Float16)p[e];
            *(half8*)(smem + W_OFF + ((wv * 4 + j) * KB_LDS + kbs) * 1024
                      + n * 64 + quad * 16) = hv;
        }
    }
    float wx4[4], bh4[4];
    #pragma unroll
    for (int j = 0; j < 4; ++j) {
        int ng = (wv * 4 + j) * 16 + n;
        wx4[j] = w_hx[ng];
        bh4[j] = b_h[ng];
    }
    // pred B-frags: wave wv owns pred K-blocks 2wv, 2wv+1; cols c<10 valid
    half8 wp[2];
    #pragma unroll
    for (int i = 0; i < 2; ++i) {
        half8 hv;
        #pragma unroll
        for (int e = 0; e < 8; ++e) hv[e] = (_Float16)0.f;
        if (n < CC) {
            const float* p = w_ph + n * HH + (wv * 2 + i) * 32 + quad * 8;
            #pragma unroll
            for (int e = 0; e < 8; ++e) hv[e] = (_Float16)p[e];
        }
        wp[i] = hv;
    }

    // zero h_0
    for (int i = tid; i < BT * HSTRIDE; i += NTHREADS) hl[i] = (_Float16)0.f;
    __syncthreads();

    const int aoff = n * (HSTRIDE * 2) + quad * 16;   // A-frag byte base
    const int woff = (wv * 4) * (KB_LDS * 1024) + n * 64 + quad * 16;

    #pragma unroll 1
    for (int t = 0; t < SS; ++t) {
        // x for this step (rows quad*4+r) — issued early, consumed after the
        // K-loop so L2 latency hides under the MFMAs
        float xr[4];
        #pragma unroll
        for (int r = 0; r < 4; ++r)
            xr[r] = x[(rowbase + quad * 4 + r) * SS + t];

        // acc init: bias only (no load dependency)
        float4v acc[4];
        #pragma unroll
        for (int j = 0; j < 4; ++j)
            #pragma unroll
            for (int r = 0; r < 4; ++r) acc[j][r] = bh4[j];

        // K loop: z += h_prev @ w_hh^T
        #pragma unroll
        for (int kb = 0; kb < KB_TOT; ++kb) {
            half8 a = *(const half8*)(smem + H_OFF + aoff + kb * 64);
            if (kb < KB_REG) {
                #pragma unroll
                for (int j = 0; j < 4; ++j)
                    acc[j] = __builtin_amdgcn_mfma_f32_16x16x32_f16(a, wr[j][kb], acc[j], 0, 0, 0);
            } else {
                #pragma unroll
                for (int j = 0; j < 4; ++j) {
                    half8 b = *(const half8*)(smem + W_OFF + woff
                                              + (j * KB_LDS + (kb - KB_REG)) * 1024);
                    acc[j] = __builtin_amdgcn_mfma_f32_16x16x32_f16(a, b, acc[j], 0, 0, 0);
                }
            }
        }

        __syncthreads();              // B1: all A-reads of h_prev done

        // z += x_t * wx ; h_new = fast_tanh(z) -> fp16 -> LDS
        #pragma unroll
        for (int j = 0; j < 4; ++j) {
            int col = (wv * 4 + j) * 16 + n;
            #pragma unroll
            for (int r = 0; r < 4; ++r) {
                float z = fmaf(xr[r], wx4[j], acc[j][r]);
                hl[(quad * 4 + r) * HSTRIDE + col] = (_Float16)fast_tanh(z);
            }
        }

        __syncthreads();              // B2: h_t visible to all waves

        // pred_t = h_t @ w_ph^T (unlagged): wave wv does K-blocks 2wv,2wv+1
        {
            float4v pa;
            #pragma unroll
            for (int r = 0; r < 4; ++r) pa[r] = 0.f;
            #pragma unroll
            for (int i = 0; i < 2; ++i) {
                half8 a2 = *(const half8*)(smem + H_OFF + aoff + (wv * 2 + i) * 64);
                pa = __builtin_amdgcn_mfma_f32_16x16x32_f16(a2, wp[i], pa, 0, 0, 0);
            }
            if (n < CC) {
                #pragma unroll
                for (int r = 0; r < 4; ++r)
                    pb[wv * PBS + (quad * 4 + r) * 12 + n] = pa[r];
            }
        }

        __syncthreads();              // B3: pred partials visible

        if (tid < BT * CC) {          // reduce 8 partials, store pred_t
            int m = tid / CC, c = tid - m * CC;
            float s = b_p[c];
            #pragma unroll
            for (int w = 0; w < NW; ++w) s += pb[w * PBS + m * 12 + c];
            out[((rowbase + m) * SS + t) * CC + c] = s;
        }
    }
}

extern "C" void kernel_launch(void* const* d_in, const int* in_sizes, int n_in,
                              void* d_out, int out_size, void* d_ws, size_t ws_size,
                              hipStream_t stream)
{
    (void)in_sizes; (void)n_in; (void)d_ws; (void)ws_size; (void)out_size;
    const float* x    = (const float*)d_in[0];
    const float* w_hx = (const float*)d_in[1];
    const float* w_hh = (const float*)d_in[2];
    const float* w_ph = (const float*)d_in[3];
    const float* b_h  = (const float*)d_in[4];
    const float* b_p  = (const float*)d_in[5];
    float* out = (float*)d_out;

    (void)hipFuncSetAttribute((const void*)rnn_persist,
                              hipFuncAttributeMaxDynamicSharedMemorySize,
                              SMEM_BYTES);
    rnn_persist<<<dim3(256 / BT), dim3(NTHREADS), SMEM_BYTES, stream>>>(
        x, w_hx, w_hh, w_ph, b_h, b_p, out);
}